// Round 10
// baseline (432.293 us; speedup 1.0000x reference)
//
#include <hip/hip_runtime.h>

#define NEIGHB 12
#define HIDD 128
#define CAP 40

typedef _Float16 half8 __attribute__((ext_vector_type(8)));
typedef float f32x4 __attribute__((ext_vector_type(4)));

// ---------------------------------------------------------------------------
// Weight pre-pack: (Wl,Wr) f32 [128][K] -> Wp f16 in MFMA-fragment order:
//   Wp[ ((t*16 + nb)*2 + s)*64 + (g*16 + col) ][8]
// n = nb*16+col (<128 = Wl), k = t*64 + s*32 + g*8 + e.
// ---------------------------------------------------------------------------
__global__ __launch_bounds__(256) void cvt_pack(
    const float* __restrict__ W1b, const float* __restrict__ W1br, _Float16* __restrict__ O1b,
    const float* __restrict__ W1a, const float* __restrict__ W1ar, _Float16* __restrict__ O1a,
    const float* __restrict__ W2b, const float* __restrict__ W2br, _Float16* __restrict__ O2b,
    const float* __restrict__ W2a, const float* __restrict__ W2ar, _Float16* __restrict__ O2a) {
    int blk = blockIdx.x;
    const float *Wl, *Wr; _Float16* out; int K, Kp, base;
    if (blk < 512)       { Wl = W1b; Wr = W1br; out = O1b; K = 480;  Kp = 512;  base = 0; }
    else if (blk < 1984) { Wl = W1a; Wr = W1ar; out = O1a; K = 1440; Kp = 1472; base = 512; }
    else if (blk < 2112) { Wl = W2b; Wr = W2br; out = O2b; K = 128;  Kp = 128;  base = 1984; }
    else                 { Wl = W2a; Wr = W2ar; out = O2a; K = 128;  Kp = 128;  base = 2112; }
    int idx = (blk - base) * 256 + threadIdx.x;
    int n = idx / Kp, k = idx - n * Kp;
    float v = 0.f;
    if (k < K) v = (n < HIDD) ? Wl[(size_t)n * K + k] : Wr[(size_t)(n - HIDD) * K + k];
    int t = k >> 6, s = (k >> 5) & 1, g = (k >> 3) & 3, e = k & 7;
    int nb = n >> 4, col = n & 15;
    size_t addr = ((((size_t)t * 16 + nb) * 2 + s) * 64 + (g * 16 + col)) * 8 + e;
    out[addr] = (_Float16)v;
}

// ---------------------------------------------------------------------------
// 512-thread GEMM body: 8 waves, wave tile 64(M) x 32(N), BK=64.
// B in registers (packed Wp, double-buffered, 4 frags/wave). LDS holds only
// the A tile (2 x 8KB dbuf, XOR swizzle g^(m&7)). One A-granule per thread.
// Epilogue: acc -> LDS ([64][128] f16, reusing A buffers) -> coalesced half8
// stores (full 64B lines; avoids partial-line write amplification, r9 PMC).
// MODE 0: A f16 direct. MODE 1: gbf(bond[.,12]). MODE 2: gbf(angle[.,144]).
// ---------------------------------------------------------------------------
template <int MODE, int KTOT, int KP>
__device__ __forceinline__ void gemm_body512(
    const void* __restrict__ Ain, const _Float16* __restrict__ Wp,
    _Float16* __restrict__ Cl, _Float16* __restrict__ Cr,
    int rows, int mb, _Float16* As) {
    constexpr int SUB  = (MODE == 2) ? 10 : 40;
    constexpr int RAWC = (MODE == 2) ? 144 : 12;
    constexpr float MU0 = (MODE == 2) ? -1.0f : 0.0f;
    constexpr float DMU = (MODE == 2) ? (2.0f / 9.0f) : (8.0f / 39.0f);
    constexpr float NL2 = -36.067375f;  // -25 * log2(e)
    constexpr int NT = KP / 64;

    const int tid = threadIdx.x;
    const int lane = tid & 63;
    const int wave = tid >> 6;      // 0..7 -> 32-col slice
    const int iBase = mb * 64;
    const int m = tid >> 3;         // 0..63 (A staging row)
    const int g = tid & 7;          // A granule
    const int g8 = g * 8;

    const int gi = min(iBase + m, rows - 1);
    const _Float16* Ap = (const _Float16*)Ain;
    const float* rr = (const float*)Ain + (size_t)gi * RAWC;

    half8 bA[4], bB[4], aExp;
    float r0v, r1v;

#define PREFB(T, DST)                                                             \
    {                                                                             \
        _Pragma("unroll")                                                         \
        for (int q = 0; q < 4; ++q) {                                             \
            int s_ = q >> 1, b_ = q & 1;                                          \
            (DST)[q] = *reinterpret_cast<const half8*>(                           \
                Wp + ((((size_t)(T) * 16 + (wave * 2 + b_)) * 2 + s_) * 64 + lane) * 8); \
        }                                                                         \
    }

#define LOADA(T)                                                                  \
    {                                                                             \
        if (MODE == 0) {                                                          \
            aExp = *reinterpret_cast<const half8*>(Ap + (size_t)gi * KP + (T) * 64 + g8); \
        } else {                                                                  \
            int k0 = (T) * 64 + g8;                                               \
            if (k0 < KTOT) {                                                      \
                int j0 = k0 / SUB;                                                \
                r0v = rr[j0];                                                     \
                if (MODE == 2) r1v = rr[min(j0 + 1, RAWC - 1)];                   \
            }                                                                     \
        }                                                                         \
    }

#define EXPAND(T)                                                                 \
    if (MODE != 0) {                                                              \
        int k0 = (T) * 64 + g8;                                                   \
        if (k0 < KTOT) {                                                          \
            int j0 = k0 / SUB, t0 = k0 - j0 * SUB;                                \
            half8 v;                                                              \
            _Pragma("unroll")                                                     \
            for (int e2 = 0; e2 < 8; ++e2) {                                      \
                int tt = t0 + e2;                                                 \
                bool c2 = (tt >= SUB);                                            \
                float dd = ((MODE == 2 && c2) ? r1v : r0v) -                      \
                           (MU0 + (float)(c2 ? tt - SUB : tt) * DMU);             \
                v[e2] = (_Float16)__builtin_amdgcn_exp2f(NL2 * dd * dd);          \
            }                                                                     \
            aExp = v;                                                             \
        } else {                                                                  \
            _Pragma("unroll")                                                     \
            for (int e2 = 0; e2 < 8; ++e2) aExp[e2] = (_Float16)0.f;              \
        }                                                                         \
    }

#define WRAS(BUF)                                                                 \
    *reinterpret_cast<half8*>(As + (BUF) * 4096 + m * 64 + ((g ^ (m & 7)) << 3)) = aExp;

#define COMPUTE(BUF, BREG)                                                        \
    {                                                                             \
        _Pragma("unroll")                                                         \
        for (int s_ = 0; s_ < 2; ++s_) {                                          \
            int cg = s_ * 4 + (lane >> 4);                                        \
            half8 af[4];                                                          \
            _Pragma("unroll")                                                     \
            for (int a_ = 0; a_ < 4; ++a_) {                                      \
                int m_ = a_ * 16 + (lane & 15);                                   \
                af[a_] = *reinterpret_cast<const half8*>(                         \
                    As + (BUF) * 4096 + m_ * 64 + ((cg ^ (m_ & 7)) << 3));        \
            }                                                                     \
            _Pragma("unroll")                                                     \
            for (int a_ = 0; a_ < 4; ++a_)                                        \
                _Pragma("unroll")                                                 \
                for (int b_ = 0; b_ < 2; ++b_)                                    \
                    acc[a_][b_] = __builtin_amdgcn_mfma_f32_16x16x32_f16(         \
                        af[a_], (BREG)[s_ * 2 + b_], acc[a_][b_], 0, 0, 0);       \
        }                                                                         \
    }

#define STEP(T, BCUR, BNEXT)                                                      \
    {                                                                             \
        __syncthreads();                                                          \
        const bool hn = (T) + 1 < NT;                                             \
        if (hn) { PREFB((T) + 1, BNEXT); LOADA((T) + 1); }                        \
        COMPUTE((T) & 1, BCUR);                                                   \
        if (hn) { EXPAND((T) + 1); WRAS(((T) + 1) & 1); }                         \
    }

    f32x4 acc[4][2];
#pragma unroll
    for (int a = 0; a < 4; ++a)
#pragma unroll
        for (int b = 0; b < 2; ++b)
#pragma unroll
            for (int r = 0; r < 4; ++r) acc[a][b][r] = 0.f;

    PREFB(0, bA);
    LOADA(0);
    EXPAND(0);
    __syncthreads();   // previous job's waves done with both A buffers
    WRAS(0);

#pragma unroll 1
    for (int t = 0; t < NT; t += 2) {
        STEP(t, bA, bB);
        if (t + 1 < NT) STEP(t + 1, bB, bA);
    }
#undef PREFB
#undef LOADA
#undef EXPAND
#undef WRAS
#undef COMPUTE
#undef STEP

    // ---- epilogue: acc -> LDS [64][128] f16 -> coalesced half8 stores ----
    _Float16* Lo = As;  // 16 KB = both A buffers, free now
#pragma unroll
    for (int h = 0; h < 2; ++h) {
        __syncthreads();                 // Lo free (K-loop or prev-half reads done)
        if ((wave >> 2) == h) {
            int colBase = (wave & 3) * 32;
#pragma unroll
            for (int a = 0; a < 4; ++a)
#pragma unroll
                for (int b = 0; b < 2; ++b)
#pragma unroll
                    for (int r = 0; r < 4; ++r) {
                        int row = a * 16 + ((lane >> 4) << 2) + r;
                        int col = colBase + b * 16 + (lane & 15);
                        Lo[row * 128 + col] = (_Float16)acc[a][b][r];
                    }
        }
        __syncthreads();
        _Float16* Cout = h ? Cr : Cl;
#pragma unroll
        for (int q = 0; q < 2; ++q) {
            int idx = tid + 512 * q;
            int row = idx >> 4, gc = (idx & 15) * 8;
            int mm = iBase + row;
            if (mm < rows)
                *reinterpret_cast<half8*>(Cout + (size_t)mm * HIDD + gc) =
                    *reinterpret_cast<const half8*>(Lo + row * 128 + gc);
        }
    }
}

// ---------------------------------------------------------------------------
// Persistent layer-1 launch: jobs [0,nA) = angle tiles, [nA,nTot) = bond.
// ---------------------------------------------------------------------------
__global__ __launch_bounds__(512, 4) void gemm_l1p(
    const float* __restrict__ bond, const _Float16* __restrict__ Wb,
    _Float16* __restrict__ Hbl, _Float16* __restrict__ Hbr,
    const float* __restrict__ angle, const _Float16* __restrict__ Wa,
    _Float16* __restrict__ Hal, _Float16* __restrict__ Har,
    int rows, int nA, int nTot) {
    __shared__ __align__(16) _Float16 As[2 * 4096];
    for (int job = blockIdx.x; job < nTot; job += gridDim.x) {
        if (job < nA)
            gemm_body512<2, 1440, 1472>(angle, Wa, Hal, Har, rows, job, As);
        else
            gemm_body512<1, 480, 512>(bond, Wb, Hbl, Hbr, rows, job - nA, As);
    }
}

// ---------------------------------------------------------------------------
// Persistent layer-2 launch: jobs [0,nA) = bond stream, [nA,nTot) = angle.
// ---------------------------------------------------------------------------
__global__ __launch_bounds__(512, 4) void gemm_l2p(
    const _Float16* __restrict__ bo, const _Float16* __restrict__ Wb,
    _Float16* __restrict__ Hbl, _Float16* __restrict__ Hbr,
    const _Float16* __restrict__ ao, const _Float16* __restrict__ Wa,
    _Float16* __restrict__ Hal, _Float16* __restrict__ Har,
    int rows, int nA, int nTot) {
    __shared__ __align__(16) _Float16 As[2 * 4096];
    for (int job = blockIdx.x; job < nTot; job += gridDim.x) {
        if (job < nA)
            gemm_body512<0, 128, 128>(bo, Wb, Hbl, Hbr, rows, job, As);
        else
            gemm_body512<0, 128, 128>(ao, Wa, Hal, Har, rows, job - nA, As);
    }
}

// ---------------------------------------------------------------------------
// Reverse-adjacency bucket build.
// ---------------------------------------------------------------------------
__global__ void build_inc(const int* __restrict__ nbr, int* __restrict__ cnt,
                          int* __restrict__ inc, int nEdges) {
    int e = blockIdx.x * blockDim.x + threadIdx.x;
    if (e >= nEdges) return;
    int d = nbr[e];
    int src = e / NEIGHB;
    int pos = atomicAdd(&cnt[d], 1);
    if (pos < CAP) inc[(size_t)d * CAP + pos] = src;
}

// ---------------------------------------------------------------------------
// Dual-stream mean-aggregate + bias + residual + relu.
// ---------------------------------------------------------------------------
__global__ __launch_bounds__(256) void agg2(
    const _Float16* __restrict__ Hbl, const _Float16* __restrict__ Hbr,
    const _Float16* __restrict__ Hal, const _Float16* __restrict__ Har,
    const int* __restrict__ cnt, const int* __restrict__ inc,
    const float* __restrict__ biasB, const float* __restrict__ biasA,
    _Float16* __restrict__ Ob, _Float16* __restrict__ Oa, int N) {
    int d = blockIdx.x * 16 + (threadIdx.x >> 4);
    if (d >= N) return;
    int c8 = (threadIdx.x & 15) * 8;
    int c = cnt[d];
    int cc = min(c, CAP);
    const int* lst = inc + (size_t)d * CAP;
    int4 q0 = *reinterpret_cast<const int4*>(lst);
    int4 q1 = *reinterpret_cast<const int4*>(lst + 4);
    int4 q2 = *reinterpret_cast<const int4*>(lst + 8);
    int idx[12] = {q0.x, q0.y, q0.z, q0.w, q1.x, q1.y, q1.z, q1.w,
                   q2.x, q2.y, q2.z, q2.w};
    half8 vb[12], va[12];
#pragma unroll
    for (int e = 0; e < 12; ++e) {
        int ii = (e < cc) ? idx[e] : 0;
        vb[e] = *reinterpret_cast<const half8*>(Hbl + (size_t)ii * HIDD + c8);
        va[e] = *reinterpret_cast<const half8*>(Hal + (size_t)ii * HIDD + c8);
    }
    float sb[8], sa[8];
#pragma unroll
    for (int j = 0; j < 8; ++j) { sb[j] = 0.f; sa[j] = 0.f; }
#pragma unroll
    for (int e = 0; e < 12; ++e) {
        float w = (e < cc) ? 1.f : 0.f;
#pragma unroll
        for (int j = 0; j < 8; ++j) {
            sb[j] = fmaf(w, (float)vb[e][j], sb[j]);
            sa[j] = fmaf(w, (float)va[e][j], sa[j]);
        }
    }
    for (int e = 12; e < cc; ++e) {
        int ii = lst[e];
        half8 xb = *reinterpret_cast<const half8*>(Hbl + (size_t)ii * HIDD + c8);
        half8 xa = *reinterpret_cast<const half8*>(Hal + (size_t)ii * HIDD + c8);
#pragma unroll
        for (int j = 0; j < 8; ++j) { sb[j] += (float)xb[j]; sa[j] += (float)xa[j]; }
    }
    float inv = 1.f / (float)max(c, 1);
    half8 rb = *reinterpret_cast<const half8*>(Hbr + (size_t)d * HIDD + c8);
    half8 ra = *reinterpret_cast<const half8*>(Har + (size_t)d * HIDD + c8);
    float4 bb0 = *reinterpret_cast<const float4*>(biasB + c8);
    float4 bb1 = *reinterpret_cast<const float4*>(biasB + c8 + 4);
    float4 ba0 = *reinterpret_cast<const float4*>(biasA + c8);
    float4 ba1 = *reinterpret_cast<const float4*>(biasA + c8 + 4);
    float fb[8] = {bb0.x, bb0.y, bb0.z, bb0.w, bb1.x, bb1.y, bb1.z, bb1.w};
    float fa[8] = {ba0.x, ba0.y, ba0.z, ba0.w, ba1.x, ba1.y, ba1.z, ba1.w};
    half8 ob, oa;
#pragma unroll
    for (int j = 0; j < 8; ++j) {
        ob[j] = (_Float16)fmaxf(sb[j] * inv + fb[j] + (float)rb[j], 0.f);
        oa[j] = (_Float16)fmaxf(sa[j] * inv + fa[j] + (float)ra[j], 0.f);
    }
    *reinterpret_cast<half8*>(Ob + (size_t)d * HIDD + c8) = ob;
    *reinterpret_cast<half8*>(Oa + (size_t)d * HIDD + c8) = oa;
}

// ---------------------------------------------------------------------------
// Per-crystal mean pool over concat(bo2, ao2) f16, then 2-class FC.
// ---------------------------------------------------------------------------
__global__ __launch_bounds__(256) void pool_fc(const _Float16* __restrict__ bo,
                                               const _Float16* __restrict__ ao,
                                               const int* __restrict__ crys,
                                               const float* __restrict__ Wfc,
                                               const float* __restrict__ bfc,
                                               float* __restrict__ out) {
    __shared__ float red0[256];
    __shared__ float red1[256];
    int b = blockIdx.x;
    int t = threadIdx.x;
    int s0 = crys[b * 2 + 0];
    int s1 = crys[b * 2 + 1];
    const _Float16* src = (t < HIDD) ? bo : ao;
    int col = t & (HIDD - 1);
    float s = 0.f;
    for (int i = s0; i < s1; ++i) s += (float)src[(size_t)i * HIDD + col];
    float pooled = s / (float)(s1 - s0);
    red0[t] = pooled * Wfc[t];
    red1[t] = pooled * Wfc[256 + t];
    __syncthreads();
    for (int off = 128; off >= 1; off >>= 1) {
        if (t < off) {
            red0[t] += red0[t + off];
            red1[t] += red1[t + off];
        }
        __syncthreads();
    }
    if (t == 0) {
        out[b * 2 + 0] = red0[0] + bfc[0];
        out[b * 2 + 1] = red1[0] + bfc[1];
    }
}

// ---------------------------------------------------------------------------
extern "C" void kernel_launch(void* const* d_in, const int* in_sizes, int n_in,
                              void* d_out, int out_size, void* d_ws, size_t ws_size,
                              hipStream_t stream) {
    const float* bond = (const float*)d_in[0];
    const float* angle = (const float*)d_in[1];
    const int* nbr = (const int*)d_in[3];
    const int* crys = (const int*)d_in[4];
    const float* W1b = (const float*)d_in[5];
    const float* b1b = (const float*)d_in[6];
    const float* W1br = (const float*)d_in[7];
    const float* W1a = (const float*)d_in[8];
    const float* b1a = (const float*)d_in[9];
    const float* W1ar = (const float*)d_in[10];
    const float* W2b = (const float*)d_in[11];
    const float* b2b = (const float*)d_in[12];
    const float* W2br = (const float*)d_in[13];
    const float* W2a = (const float*)d_in[14];
    const float* b2a = (const float*)d_in[15];
    const float* W2ar = (const float*)d_in[16];
    const float* Wfc = (const float*)d_in[17];
    const float* bfc = (const float*)d_in[18];
    float* out = (float*)d_out;

    const int N = in_sizes[2];      // 50000
    const int B = in_sizes[4] / 2;  // 500
    const int nEdges = N * NEIGHB;

    // ---- workspace carve (~112 MB) ----
    char* p = (char*)d_ws;
    _Float16* Hbl = (_Float16*)p;  p += (size_t)N * HIDD * 2;
    _Float16* Hbr = (_Float16*)p;  p += (size_t)N * HIDD * 2;
    _Float16* Hal = (_Float16*)p;  p += (size_t)N * HIDD * 2;
    _Float16* Har = (_Float16*)p;  p += (size_t)N * HIDD * 2;
    _Float16* bo  = (_Float16*)p;  p += (size_t)N * HIDD * 2;
    _Float16* ao  = (_Float16*)p;  p += (size_t)N * HIDD * 2;
    _Float16* bo2 = (_Float16*)p;  p += (size_t)N * HIDD * 2;
    _Float16* ao2 = (_Float16*)p;  p += (size_t)N * HIDD * 2;
    int* cnt = (int*)p;            p += (size_t)N * 4;
    int* inc = (int*)p;            p += (size_t)N * CAP * 4;
    _Float16* W1bp = (_Float16*)p; p += 256 * 512 * 2;
    _Float16* W1ap = (_Float16*)p; p += 256 * 1472 * 2;
    _Float16* W2bp = (_Float16*)p; p += 256 * 128 * 2;
    _Float16* W2ap = (_Float16*)p;

    hipMemsetAsync(cnt, 0, (size_t)N * 4, stream);
    build_inc<<<(nEdges + 255) / 256, 256, 0, stream>>>(nbr, cnt, inc, nEdges);
    cvt_pack<<<2240, 256, 0, stream>>>(W1b, W1br, W1bp, W1a, W1ar, W1ap,
                                       W2b, W2br, W2bp, W2a, W2ar, W2ap);

    const int gB = (N + 63) / 64;    // 782 tiles per stream
    const int aB = (N + 15) / 16;    // 3125

    // layer 1: persistent merged launch (angle jobs first), then agg
    gemm_l1p<<<512, 512, 0, stream>>>(bond, W1bp, Hbl, Hbr,
                                      angle, W1ap, Hal, Har, N, gB, gB * 2);
    agg2<<<aB, 256, 0, stream>>>(Hbl, Hbr, Hal, Har, cnt, inc, b1b, b1a, bo, ao, N);
    // layer 2: persistent merged launch, then agg
    gemm_l2p<<<512, 512, 0, stream>>>(bo, W2bp, Hbl, Hbr,
                                      ao, W2ap, Hal, Har, N, gB, gB * 2);
    agg2<<<aB, 256, 0, stream>>>(Hbl, Hbr, Hal, Har, cnt, inc, b2b, b2a, bo2, ao2, N);

    pool_fc<<<B, 256, 0, stream>>>(bo2, ao2, crys, Wfc, bfc, out);
}

// Round 12
// 359.353 us; speedup vs baseline: 1.2030x; 1.2030x over previous
//
#include <hip/hip_runtime.h>

#define NEIGHB 12
#define HIDD 128
#define CAP 40

typedef _Float16 half8 __attribute__((ext_vector_type(8)));
typedef float f32x4 __attribute__((ext_vector_type(4)));

// ---------------------------------------------------------------------------
// Weight pre-pack: (Wl,Wr) f32 [128][K] -> Wp f16 in MFMA-fragment order:
//   Wp[ ((t*16 + nb)*2 + s)*64 + (g*16 + col) ][8]
// n = nb*16+col (<128 = Wl), k = t*64 + s*32 + g*8 + e.
// ---------------------------------------------------------------------------
__global__ __launch_bounds__(256) void cvt_pack(
    const float* __restrict__ W1b, const float* __restrict__ W1br, _Float16* __restrict__ O1b,
    const float* __restrict__ W1a, const float* __restrict__ W1ar, _Float16* __restrict__ O1a,
    const float* __restrict__ W2b, const float* __restrict__ W2br, _Float16* __restrict__ O2b,
    const float* __restrict__ W2a, const float* __restrict__ W2ar, _Float16* __restrict__ O2a) {
    int blk = blockIdx.x;
    const float *Wl, *Wr; _Float16* out; int K, Kp, base;
    if (blk < 512)       { Wl = W1b; Wr = W1br; out = O1b; K = 480;  Kp = 512;  base = 0; }
    else if (blk < 1984) { Wl = W1a; Wr = W1ar; out = O1a; K = 1440; Kp = 1472; base = 512; }
    else if (blk < 2112) { Wl = W2b; Wr = W2br; out = O2b; K = 128;  Kp = 128;  base = 1984; }
    else                 { Wl = W2a; Wr = W2ar; out = O2a; K = 128;  Kp = 128;  base = 2112; }
    int idx = (blk - base) * 256 + threadIdx.x;
    int n = idx / Kp, k = idx - n * Kp;
    float v = 0.f;
    if (k < K) v = (n < HIDD) ? Wl[(size_t)n * K + k] : Wr[(size_t)(n - HIDD) * K + k];
    int t = k >> 6, s = (k >> 5) & 1, g = (k >> 3) & 3, e = k & 7;
    int nb = n >> 4, col = n & 15;
    size_t addr = ((((size_t)t * 16 + nb) * 2 + s) * 64 + (g * 16 + col)) * 8 + e;
    out[addr] = (_Float16)v;
}

// ---------------------------------------------------------------------------
// 512-thread GEMM body: 8 waves, wave tile 64(M) x 32(N), BK=64.
// B in registers (packed Wp, double-buffered, 4 frags/wave). LDS holds only
// the A tile (2 x 8KB dbuf, XOR swizzle g^(m&7)). One A-granule per thread.
// launch_bounds(512,3): VGPR cap ~170 -> NO scratch spill (r9/r10 lesson:
// (512,4)'s 64-reg cap spilled ~95MB/dispatch to HBM).
// MODE 0: A f16 direct. MODE 1: gbf(bond[.,12]). MODE 2: gbf(angle[.,144]).
// ---------------------------------------------------------------------------
template <int MODE, int KTOT, int KP>
__device__ __forceinline__ void gemm_body512(
    const void* __restrict__ Ain, const _Float16* __restrict__ Wp,
    _Float16* __restrict__ Cl, _Float16* __restrict__ Cr,
    int rows, int mb, _Float16* As) {
    constexpr int SUB  = (MODE == 2) ? 10 : 40;
    constexpr int RAWC = (MODE == 2) ? 144 : 12;
    constexpr float MU0 = (MODE == 2) ? -1.0f : 0.0f;
    constexpr float DMU = (MODE == 2) ? (2.0f / 9.0f) : (8.0f / 39.0f);
    constexpr float NL2 = -36.067375f;  // -25 * log2(e)
    constexpr int NT = KP / 64;

    const int tid = threadIdx.x;
    const int lane = tid & 63;
    const int wave = tid >> 6;      // 0..7 -> 32-col slice
    const int iBase = mb * 64;
    const int m = tid >> 3;         // 0..63 (A staging row)
    const int g = tid & 7;          // A granule
    const int g8 = g * 8;

    const int gi = min(iBase + m, rows - 1);
    const _Float16* Ap = (const _Float16*)Ain;
    const float* rr = (const float*)Ain + (size_t)gi * RAWC;

    half8 bA[4], bB[4], aExp;
    float r0v, r1v;

#define PREFB(T, DST)                                                             \
    {                                                                             \
        _Pragma("unroll")                                                         \
        for (int q = 0; q < 4; ++q) {                                             \
            int s_ = q >> 1, b_ = q & 1;                                          \
            (DST)[q] = *reinterpret_cast<const half8*>(                           \
                Wp + ((((size_t)(T) * 16 + (wave * 2 + b_)) * 2 + s_) * 64 + lane) * 8); \
        }                                                                         \
    }

#define LOADA(T)                                                                  \
    {                                                                             \
        if (MODE == 0) {                                                          \
            aExp = *reinterpret_cast<const half8*>(Ap + (size_t)gi * KP + (T) * 64 + g8); \
        } else {                                                                  \
            int k0 = (T) * 64 + g8;                                               \
            if (k0 < KTOT) {                                                      \
                int j0 = k0 / SUB;                                                \
                r0v = rr[j0];                                                     \
                if (MODE == 2) r1v = rr[min(j0 + 1, RAWC - 1)];                   \
            }                                                                     \
        }                                                                         \
    }

#define EXPAND(T)                                                                 \
    if (MODE != 0) {                                                              \
        int k0 = (T) * 64 + g8;                                                   \
        if (k0 < KTOT) {                                                          \
            int j0 = k0 / SUB, t0 = k0 - j0 * SUB;                                \
            half8 v;                                                              \
            _Pragma("unroll")                                                     \
            for (int e2 = 0; e2 < 8; ++e2) {                                      \
                int tt = t0 + e2;                                                 \
                bool c2 = (tt >= SUB);                                            \
                float dd = ((MODE == 2 && c2) ? r1v : r0v) -                      \
                           (MU0 + (float)(c2 ? tt - SUB : tt) * DMU);             \
                v[e2] = (_Float16)__builtin_amdgcn_exp2f(NL2 * dd * dd);          \
            }                                                                     \
            aExp = v;                                                             \
        } else {                                                                  \
            _Pragma("unroll")                                                     \
            for (int e2 = 0; e2 < 8; ++e2) aExp[e2] = (_Float16)0.f;              \
        }                                                                         \
    }

#define WRAS(BUF)                                                                 \
    *reinterpret_cast<half8*>(As + (BUF) * 4096 + m * 64 + ((g ^ (m & 7)) << 3)) = aExp;

#define COMPUTE(BUF, BREG)                                                        \
    {                                                                             \
        _Pragma("unroll")                                                         \
        for (int s_ = 0; s_ < 2; ++s_) {                                          \
            int cg = s_ * 4 + (lane >> 4);                                        \
            half8 af[4];                                                          \
            _Pragma("unroll")                                                     \
            for (int a_ = 0; a_ < 4; ++a_) {                                      \
                int m_ = a_ * 16 + (lane & 15);                                   \
                af[a_] = *reinterpret_cast<const half8*>(                         \
                    As + (BUF) * 4096 + m_ * 64 + ((cg ^ (m_ & 7)) << 3));        \
            }                                                                     \
            _Pragma("unroll")                                                     \
            for (int a_ = 0; a_ < 4; ++a_)                                        \
                _Pragma("unroll")                                                 \
                for (int b_ = 0; b_ < 2; ++b_)                                    \
                    acc[a_][b_] = __builtin_amdgcn_mfma_f32_16x16x32_f16(         \
                        af[a_], (BREG)[s_ * 2 + b_], acc[a_][b_], 0, 0, 0);       \
        }                                                                         \
    }

#define STEP(T, BCUR, BNEXT)                                                      \
    {                                                                             \
        __syncthreads();                                                          \
        const bool hn = (T) + 1 < NT;                                             \
        if (hn) { PREFB((T) + 1, BNEXT); LOADA((T) + 1); }                        \
        COMPUTE((T) & 1, BCUR);                                                   \
        if (hn) { EXPAND((T) + 1); WRAS(((T) + 1) & 1); }                         \
    }

    f32x4 acc[4][2];
#pragma unroll
    for (int a = 0; a < 4; ++a)
#pragma unroll
        for (int b = 0; b < 2; ++b)
#pragma unroll
            for (int r = 0; r < 4; ++r) acc[a][b][r] = 0.f;

    PREFB(0, bA);
    LOADA(0);
    EXPAND(0);
    WRAS(0);

#pragma unroll 1
    for (int t = 0; t < NT; t += 2) {
        STEP(t, bA, bB);
        if (t + 1 < NT) STEP(t + 1, bB, bA);
    }
#undef PREFB
#undef LOADA
#undef EXPAND
#undef WRAS
#undef COMPUTE
#undef STEP

    // ---- epilogue: direct 32B-chunk stores (clean traffic in r7 PMC) ----
    _Float16* Cout = (wave < 4) ? Cl : Cr;
    int nBase = (wave & 3) * 32;
#pragma unroll
    for (int a = 0; a < 4; ++a) {
        int mrel = a * 16 + ((lane >> 4) << 2);
#pragma unroll
        for (int r = 0; r < 4; ++r) {
            int mm = iBase + mrel + r;
            if (mm < rows) {
#pragma unroll
                for (int b = 0; b < 2; ++b) {
                    int n = nBase + b * 16 + (lane & 15);
                    Cout[(size_t)mm * HIDD + n] = (_Float16)acc[a][b][r];
                }
            }
        }
    }
}

// ---------------------------------------------------------------------------
// Layer-1 merged launch (non-persistent): [0,nA) angle tiles, [nA,..) bond.
// ---------------------------------------------------------------------------
__global__ __launch_bounds__(512, 3) void gemm_l1p(
    const float* __restrict__ bond, const _Float16* __restrict__ Wb,
    _Float16* __restrict__ Hbl, _Float16* __restrict__ Hbr,
    const float* __restrict__ angle, const _Float16* __restrict__ Wa,
    _Float16* __restrict__ Hal, _Float16* __restrict__ Har,
    int rows, int nA) {
    __shared__ __align__(16) _Float16 As[2 * 4096];
    int job = blockIdx.x;
    if (job < nA)
        gemm_body512<2, 1440, 1472>(angle, Wa, Hal, Har, rows, job, As);
    else
        gemm_body512<1, 480, 512>(bond, Wb, Hbl, Hbr, rows, job - nA, As);
}

// ---------------------------------------------------------------------------
// Layer-2 merged launch (non-persistent): [0,nA) bond stream, [nA,..) angle.
// ---------------------------------------------------------------------------
__global__ __launch_bounds__(512, 3) void gemm_l2p(
    const _Float16* __restrict__ bo, const _Float16* __restrict__ Wb,
    _Float16* __restrict__ Hbl, _Float16* __restrict__ Hbr,
    const _Float16* __restrict__ ao, const _Float16* __restrict__ Wa,
    _Float16* __restrict__ Hal, _Float16* __restrict__ Har,
    int rows, int nA) {
    __shared__ __align__(16) _Float16 As[2 * 4096];
    int job = blockIdx.x;
    if (job < nA)
        gemm_body512<0, 128, 128>(bo, Wb, Hbl, Hbr, rows, job, As);
    else
        gemm_body512<0, 128, 128>(ao, Wa, Hal, Har, rows, job - nA, As);
}

// ---------------------------------------------------------------------------
// Reverse-adjacency bucket build.
// ---------------------------------------------------------------------------
__global__ void build_inc(const int* __restrict__ nbr, int* __restrict__ cnt,
                          int* __restrict__ inc, int nEdges) {
    int e = blockIdx.x * blockDim.x + threadIdx.x;
    if (e >= nEdges) return;
    int d = nbr[e];
    int src = e / NEIGHB;
    int pos = atomicAdd(&cnt[d], 1);
    if (pos < CAP) inc[(size_t)d * CAP + pos] = src;
}

// ---------------------------------------------------------------------------
// Dual-stream mean-aggregate + bias + residual + relu.
// ---------------------------------------------------------------------------
__global__ __launch_bounds__(256) void agg2(
    const _Float16* __restrict__ Hbl, const _Float16* __restrict__ Hbr,
    const _Float16* __restrict__ Hal, const _Float16* __restrict__ Har,
    const int* __restrict__ cnt, const int* __restrict__ inc,
    const float* __restrict__ biasB, const float* __restrict__ biasA,
    _Float16* __restrict__ Ob, _Float16* __restrict__ Oa, int N) {
    int d = blockIdx.x * 16 + (threadIdx.x >> 4);
    if (d >= N) return;
    int c8 = (threadIdx.x & 15) * 8;
    int c = cnt[d];
    int cc = min(c, CAP);
    const int* lst = inc + (size_t)d * CAP;
    int4 q0 = *reinterpret_cast<const int4*>(lst);
    int4 q1 = *reinterpret_cast<const int4*>(lst + 4);
    int4 q2 = *reinterpret_cast<const int4*>(lst + 8);
    int idx[12] = {q0.x, q0.y, q0.z, q0.w, q1.x, q1.y, q1.z, q1.w,
                   q2.x, q2.y, q2.z, q2.w};
    half8 vb[12], va[12];
#pragma unroll
    for (int e = 0; e < 12; ++e) {
        int ii = (e < cc) ? idx[e] : 0;
        vb[e] = *reinterpret_cast<const half8*>(Hbl + (size_t)ii * HIDD + c8);
        va[e] = *reinterpret_cast<const half8*>(Hal + (size_t)ii * HIDD + c8);
    }
    float sb[8], sa[8];
#pragma unroll
    for (int j = 0; j < 8; ++j) { sb[j] = 0.f; sa[j] = 0.f; }
#pragma unroll
    for (int e = 0; e < 12; ++e) {
        float w = (e < cc) ? 1.f : 0.f;
#pragma unroll
        for (int j = 0; j < 8; ++j) {
            sb[j] = fmaf(w, (float)vb[e][j], sb[j]);
            sa[j] = fmaf(w, (float)va[e][j], sa[j]);
        }
    }
    for (int e = 12; e < cc; ++e) {
        int ii = lst[e];
        half8 xb = *reinterpret_cast<const half8*>(Hbl + (size_t)ii * HIDD + c8);
        half8 xa = *reinterpret_cast<const half8*>(Hal + (size_t)ii * HIDD + c8);
#pragma unroll
        for (int j = 0; j < 8; ++j) { sb[j] += (float)xb[j]; sa[j] += (float)xa[j]; }
    }
    float inv = 1.f / (float)max(c, 1);
    half8 rb = *reinterpret_cast<const half8*>(Hbr + (size_t)d * HIDD + c8);
    half8 ra = *reinterpret_cast<const half8*>(Har + (size_t)d * HIDD + c8);
    float4 bb0 = *reinterpret_cast<const float4*>(biasB + c8);
    float4 bb1 = *reinterpret_cast<const float4*>(biasB + c8 + 4);
    float4 ba0 = *reinterpret_cast<const float4*>(biasA + c8);
    float4 ba1 = *reinterpret_cast<const float4*>(biasA + c8 + 4);
    float fb[8] = {bb0.x, bb0.y, bb0.z, bb0.w, bb1.x, bb1.y, bb1.z, bb1.w};
    float fa[8] = {ba0.x, ba0.y, ba0.z, ba0.w, ba1.x, ba1.y, ba1.z, ba1.w};
    half8 ob, oa;
#pragma unroll
    for (int j = 0; j < 8; ++j) {
        ob[j] = (_Float16)fmaxf(sb[j] * inv + fb[j] + (float)rb[j], 0.f);
        oa[j] = (_Float16)fmaxf(sa[j] * inv + fa[j] + (float)ra[j], 0.f);
    }
    *reinterpret_cast<half8*>(Ob + (size_t)d * HIDD + c8) = ob;
    *reinterpret_cast<half8*>(Oa + (size_t)d * HIDD + c8) = oa;
}

// ---------------------------------------------------------------------------
// Per-crystal mean pool over concat(bo2, ao2) f16, then 2-class FC.
// ---------------------------------------------------------------------------
__global__ __launch_bounds__(256) void pool_fc(const _Float16* __restrict__ bo,
                                               const _Float16* __restrict__ ao,
                                               const int* __restrict__ crys,
                                               const float* __restrict__ Wfc,
                                               const float* __restrict__ bfc,
                                               float* __restrict__ out) {
    __shared__ float red0[256];
    __shared__ float red1[256];
    int b = blockIdx.x;
    int t = threadIdx.x;
    int s0 = crys[b * 2 + 0];
    int s1 = crys[b * 2 + 1];
    const _Float16* src = (t < HIDD) ? bo : ao;
    int col = t & (HIDD - 1);
    float s = 0.f;
    for (int i = s0; i < s1; ++i) s += (float)src[(size_t)i * HIDD + col];
    float pooled = s / (float)(s1 - s0);
    red0[t] = pooled * Wfc[t];
    red1[t] = pooled * Wfc[256 + t];
    __syncthreads();
    for (int off = 128; off >= 1; off >>= 1) {
        if (t < off) {
            red0[t] += red0[t + off];
            red1[t] += red1[t + off];
        }
        __syncthreads();
    }
    if (t == 0) {
        out[b * 2 + 0] = red0[0] + bfc[0];
        out[b * 2 + 1] = red1[0] + bfc[1];
    }
}

// ---------------------------------------------------------------------------
extern "C" void kernel_launch(void* const* d_in, const int* in_sizes, int n_in,
                              void* d_out, int out_size, void* d_ws, size_t ws_size,
                              hipStream_t stream) {
    const float* bond = (const float*)d_in[0];
    const float* angle = (const float*)d_in[1];
    const int* nbr = (const int*)d_in[3];
    const int* crys = (const int*)d_in[4];
    const float* W1b = (const float*)d_in[5];
    const float* b1b = (const float*)d_in[6];
    const float* W1br = (const float*)d_in[7];
    const float* W1a = (const float*)d_in[8];
    const float* b1a = (const float*)d_in[9];
    const float* W1ar = (const float*)d_in[10];
    const float* W2b = (const float*)d_in[11];
    const float* b2b = (const float*)d_in[12];
    const float* W2br = (const float*)d_in[13];
    const float* W2a = (const float*)d_in[14];
    const float* b2a = (const float*)d_in[15];
    const float* W2ar = (const float*)d_in[16];
    const float* Wfc = (const float*)d_in[17];
    const float* bfc = (const float*)d_in[18];
    float* out = (float*)d_out;

    const int N = in_sizes[2];      // 50000
    const int B = in_sizes[4] / 2;  // 500
    const int nEdges = N * NEIGHB;

    // ---- workspace carve (~112 MB) ----
    char* p = (char*)d_ws;
    _Float16* Hbl = (_Float16*)p;  p += (size_t)N * HIDD * 2;
    _Float16* Hbr = (_Float16*)p;  p += (size_t)N * HIDD * 2;
    _Float16* Hal = (_Float16*)p;  p += (size_t)N * HIDD * 2;
    _Float16* Har = (_Float16*)p;  p += (size_t)N * HIDD * 2;
    _Float16* bo  = (_Float16*)p;  p += (size_t)N * HIDD * 2;
    _Float16* ao  = (_Float16*)p;  p += (size_t)N * HIDD * 2;
    _Float16* bo2 = (_Float16*)p;  p += (size_t)N * HIDD * 2;
    _Float16* ao2 = (_Float16*)p;  p += (size_t)N * HIDD * 2;
    int* cnt = (int*)p;            p += (size_t)N * 4;
    int* inc = (int*)p;            p += (size_t)N * CAP * 4;
    _Float16* W1bp = (_Float16*)p; p += 256 * 512 * 2;
    _Float16* W1ap = (_Float16*)p; p += 256 * 1472 * 2;
    _Float16* W2bp = (_Float16*)p; p += 256 * 128 * 2;
    _Float16* W2ap = (_Float16*)p;

    hipMemsetAsync(cnt, 0, (size_t)N * 4, stream);
    build_inc<<<(nEdges + 255) / 256, 256, 0, stream>>>(nbr, cnt, inc, nEdges);
    cvt_pack<<<2240, 256, 0, stream>>>(W1b, W1br, W1bp, W1a, W1ar, W1ap,
                                       W2b, W2br, W2bp, W2a, W2ar, W2ap);

    const int gB = (N + 63) / 64;    // 782 tiles per stream
    const int aB = (N + 15) / 16;    // 3125

    // layer 1: merged launch (angle tiles first), then agg
    gemm_l1p<<<gB * 2, 512, 0, stream>>>(bond, W1bp, Hbl, Hbr,
                                         angle, W1ap, Hal, Har, N, gB);
    agg2<<<aB, 256, 0, stream>>>(Hbl, Hbr, Hal, Har, cnt, inc, b1b, b1a, bo, ao, N);
    // layer 2: merged launch, then agg
    gemm_l2p<<<gB * 2, 512, 0, stream>>>(bo, W2bp, Hbl, Hbr,
                                         ao, W2ap, Hal, Har, N, gB);
    agg2<<<aB, 256, 0, stream>>>(Hbl, Hbr, Hal, Har, cnt, inc, b2b, b2a, bo2, ao2, N);

    pool_fc<<<B, 256, 0, stream>>>(bo2, ao2, crys, Wfc, bfc, out);
}